// Round 9
// baseline (259.058 us; speedup 1.0000x reference)
//
#include <hip/hip_runtime.h>
#include <stdint.h>

// Problem constants (fixed by setup_inputs)
constexpr int B_SZ     = 128;
constexpr int IN_CAPS  = 1152;
constexpr int OUT_CAPS = 32;
constexpr int OUT_D    = 16;

constexpr int THREADS  = 512;               // 8 waves
constexpr int GB       = 8;                 // batches per block
constexpr int TILE_R   = 64;                // i-rows per W tile
constexpr int NTILE    = IN_CAPS / TILE_R;  // 18

// async global->LDS, 16B per lane, dest = wave-uniform base + lane*16
typedef const uint32_t __attribute__((address_space(1)))* gptr_t;
typedef uint32_t       __attribute__((address_space(3)))* lptr_t;
__device__ __forceinline__ void async_copy16(const float* g, float* l) {
    __builtin_amdgcn_global_load_lds((gptr_t)g, (lptr_t)l, 16, 0, 0);
}

// Sweep/recompute structure (R8) + 4-batch register reuse per LDS read (new).
// R8 was LDS-issue-bound: 1728 ds_read_b128/thread because 8 threads re-read
// the same W row (one per batch). Now thread = (ipar, mq, bp) holds FOUR
// batches' u in regs and covers one m-quarter: 8 reads/tile/thread, each
// feeding 16 FMA -> 4x fewer LDS instructions.
//
// Routing identity (R8): logit_k[b,i] = (sum_{k'<k} v_k')·u_hat[b,i], so only
// vsum[16] persists between sweeps; u_hat recomputed on the fly, never stored.
// LDS tile layout [chunk c=(4n+mq)][row]: measured conflict-free in R8
// (180K vs 9.4M) - slot mod 8 = row low-3 bits -> 4 addrs/bank-quad = floor.
__global__ __launch_bounds__(THREADS, 2) void caps_route(
    const float* __restrict__ u,   // [B, IN_CAPS, 8]
    const float* __restrict__ w,   // [IN_CAPS, OUT_CAPS, 8, 16]
    float* __restrict__ out)       // [B, OUT_CAPS, OUT_D]
{
    __shared__ __align__(16) float tile[2][32 * TILE_R * 4]; // 2 x 32 KB
    __shared__ __align__(16) float red[64 * 20];             // [wv*8+slot][16st+4den]
    __shared__ float vlds[GB * OUT_D];                       // running vsum

    // Bijective XCD swizzle (512 % 8 == 0): j-major ids -> each XCD's L2
    // holds 4 j-columns (2.3 MB < 4 MB).
    const int nwg = gridDim.x;               // 512
    const int bid = blockIdx.x;
    const int wid = (bid & 7) * (nwg >> 3) + (bid >> 3);
    const int j   = wid >> 4;                // 0..31
    const int b0  = (wid & 15) * GB;         // 0..120 step 8

    const int tid  = threadIdx.x;
    const int lane = tid & 63;
    const int wv   = tid >> 6;               // wave 0..7
    const int bp   = tid & 1;                // batch-half (4 b's each)
    const int mq   = (tid >> 1) & 3;         // m-quarter
    const int ipar = tid >> 3;               // i-row in tile, 0..63

    const float* wj  = w + (size_t)j * 128;  // + i*4096 + c*4
    const float* myu = u + ((size_t)(b0 + bp * 4) * IN_CAPS + ipar) * 8;

    float st[4][4];      // s~ partial per (bi, k)
    float vs[4][4];      // vsum slice (my m-quarter) per bi
    float den[4];        // softmax denominator partial per bi

    // stage W tile T into LDS buffer NB: chunk c's 64-row column = 1 KB =
    // exactly one wave-issue (dest wave-uniform, source per-lane row)
    #define STAGE(NB, T)                                                      \
    do {                                                                      \
        _Pragma("unroll")                                                     \
        for (int q = 0; q < 4; ++q) {                                         \
            const int c = wv * 4 + q;                                         \
            const float* gsrc =                                               \
                wj + (size_t)((T) * TILE_R + lane) * 4096 + c * 4;            \
            async_copy16(gsrc, &tile[(NB)][c * 256]);                         \
        }                                                                     \
    } while (0)

    // compute u_hat slice for (4 b's, i=T*64+ipar, m-quarter) and fold into
    // sweep-K accumulators. K literal -> branch folds away.
    #define COMP(NB, K, T)                                                    \
    do {                                                                      \
        const float* up = myu + (size_t)(T) * (TILE_R * 8);                   \
        const float4 a0 = *reinterpret_cast<const float4*>(up);               \
        const float4 a1 = *reinterpret_cast<const float4*>(up + 4);           \
        const float4 b1 = *reinterpret_cast<const float4*>(up + 9216);        \
        const float4 b2 = *reinterpret_cast<const float4*>(up + 9220);        \
        const float4 c1 = *reinterpret_cast<const float4*>(up + 18432);       \
        const float4 c2 = *reinterpret_cast<const float4*>(up + 18436);       \
        const float4 d1 = *reinterpret_cast<const float4*>(up + 27648);       \
        const float4 d2 = *reinterpret_cast<const float4*>(up + 27652);       \
        const float uc0[8] = {a0.x, a0.y, a0.z, a0.w, a1.x, a1.y, a1.z, a1.w};\
        const float uc1[8] = {b1.x, b1.y, b1.z, b1.w, b2.x, b2.y, b2.z, b2.w};\
        const float uc2[8] = {c1.x, c1.y, c1.z, c1.w, c2.x, c2.y, c2.z, c2.w};\
        const float uc3[8] = {d1.x, d1.y, d1.z, d1.w, d2.x, d2.y, d2.z, d2.w};\
        float uh[4][4];                                                       \
        _Pragma("unroll")                                                     \
        for (int bi = 0; bi < 4; ++bi)                                        \
            _Pragma("unroll")                                                 \
            for (int k2 = 0; k2 < 4; ++k2) uh[bi][k2] = 0.0f;                 \
        const float* tb = &tile[(NB)][mq * 256 + ipar * 4];                   \
        _Pragma("unroll")                                                     \
        for (int n = 0; n < 8; ++n) {                                         \
            const float4 w4 = *reinterpret_cast<const float4*>(tb + n * 1024);\
            uh[0][0] = fmaf(uc0[n], w4.x, uh[0][0]);                          \
            uh[0][1] = fmaf(uc0[n], w4.y, uh[0][1]);                          \
            uh[0][2] = fmaf(uc0[n], w4.z, uh[0][2]);                          \
            uh[0][3] = fmaf(uc0[n], w4.w, uh[0][3]);                          \
            uh[1][0] = fmaf(uc1[n], w4.x, uh[1][0]);                          \
            uh[1][1] = fmaf(uc1[n], w4.y, uh[1][1]);                          \
            uh[1][2] = fmaf(uc1[n], w4.z, uh[1][2]);                          \
            uh[1][3] = fmaf(uc1[n], w4.w, uh[1][3]);                          \
            uh[2][0] = fmaf(uc2[n], w4.x, uh[2][0]);                          \
            uh[2][1] = fmaf(uc2[n], w4.y, uh[2][1]);                          \
            uh[2][2] = fmaf(uc2[n], w4.z, uh[2][2]);                          \
            uh[2][3] = fmaf(uc2[n], w4.w, uh[2][3]);                          \
            uh[3][0] = fmaf(uc3[n], w4.x, uh[3][0]);                          \
            uh[3][1] = fmaf(uc3[n], w4.y, uh[3][1]);                          \
            uh[3][2] = fmaf(uc3[n], w4.z, uh[3][2]);                          \
            uh[3][3] = fmaf(uc3[n], w4.w, uh[3][3]);                          \
        }                                                                     \
        if ((K) == 0) {                                                       \
            _Pragma("unroll")                                                 \
            for (int bi = 0; bi < 4; ++bi)                                    \
                _Pragma("unroll")                                             \
                for (int k2 = 0; k2 < 4; ++k2) st[bi][k2] += uh[bi][k2];      \
        } else {                                                              \
            _Pragma("unroll")                                                 \
            for (int bi = 0; bi < 4; ++bi) {                                  \
                float lp = uh[bi][0] * vs[bi][0];                             \
                lp = fmaf(uh[bi][1], vs[bi][1], lp);                          \
                lp = fmaf(uh[bi][2], vs[bi][2], lp);                          \
                lp = fmaf(uh[bi][3], vs[bi][3], lp);                          \
                lp += __shfl_xor(lp, 2);   /* reduce over mq bit 0 */         \
                lp += __shfl_xor(lp, 4);   /* reduce over mq bit 1 */         \
                const float e = __expf(lp);                                   \
                den[bi] += e;                                                 \
                _Pragma("unroll")                                             \
                for (int k2 = 0; k2 < 4; ++k2)                                \
                    st[bi][k2] = fmaf(e, uh[bi][k2], st[bi][k2]);             \
            }                                                                 \
        }                                                                     \
    } while (0)

    // end-of-sweep: reduce st/den over ipar (wave shfl + LDS over waves),
    // squash, update vlds or write output.
    #define REDUCE(K)                                                         \
    do {                                                                      \
        _Pragma("unroll")                                                     \
        for (int bi = 0; bi < 4; ++bi) {                                      \
            _Pragma("unroll")                                                 \
            for (int k2 = 0; k2 < 4; ++k2) {                                  \
                st[bi][k2] += __shfl_xor(st[bi][k2], 8);                      \
                st[bi][k2] += __shfl_xor(st[bi][k2], 16);                     \
                st[bi][k2] += __shfl_xor(st[bi][k2], 32);                     \
            }                                                                 \
            if ((K) > 0) {                                                    \
                den[bi] += __shfl_xor(den[bi], 8);                            \
                den[bi] += __shfl_xor(den[bi], 16);                           \
                den[bi] += __shfl_xor(den[bi], 32);                           \
            }                                                                 \
        }                                                                     \
        if (lane < 8) {   /* lane == mq*2+bp of ipar-group 0 */               \
            float* rb = &red[(wv * 8 + lane) * 20];                           \
            *reinterpret_cast<float4*>(rb +  0) =                             \
                make_float4(st[0][0], st[0][1], st[0][2], st[0][3]);          \
            *reinterpret_cast<float4*>(rb +  4) =                             \
                make_float4(st[1][0], st[1][1], st[1][2], st[1][3]);          \
            *reinterpret_cast<float4*>(rb +  8) =                             \
                make_float4(st[2][0], st[2][1], st[2][2], st[2][3]);          \
            *reinterpret_cast<float4*>(rb + 12) =                             \
                make_float4(st[3][0], st[3][1], st[3][2], st[3][3]);          \
            *reinterpret_cast<float4*>(rb + 16) =                             \
                make_float4(den[0], den[1], den[2], den[3]);                  \
        }                                                                     \
        __syncthreads();                                                      \
        if (tid < 128) {                                                      \
            const int b_ = tid >> 4, m_ = tid & 15;                           \
            const int slot = (m_ >> 2) * 2 + (b_ >> 2);  /* mq*2+bp */        \
            const int off  = (b_ & 3) * 4 + (m_ & 3);                         \
            float acc = 0.0f, ds = 0.0f;                                      \
            _Pragma("unroll")                                                 \
            for (int q = 0; q < 8; ++q) {                                     \
                acc += red[(q * 8 + slot) * 20 + off];                        \
                ds  += red[(q * 8 + slot) * 20 + 16 + (b_ & 3)];              \
            }                                                                 \
            const float dn = ((K) == 0) ? (float)IN_CAPS : ds;                \
            const float sm = acc / dn;                                        \
            float s2 = sm * sm;                                               \
            s2 += __shfl_xor(s2, 1); s2 += __shfl_xor(s2, 2);                 \
            s2 += __shfl_xor(s2, 4); s2 += __shfl_xor(s2, 8);                 \
            const float v_ = sm * (s2 / (1.0f + s2)) * rsqrtf(s2 + 1e-8f);    \
            if ((K) == 0)      vlds[b_ * 16 + m_] = v_;                       \
            else if ((K) == 1) vlds[b_ * 16 + m_] += v_;                      \
            else out[((size_t)(b0 + b_) * OUT_CAPS + j) * OUT_D + m_] = v_;   \
        }                                                                     \
        if ((K) < 2) __syncthreads();                                         \
    } while (0)

    // one sweep over all 1152 i, double-buffered; stage(T+1) issued before
    // COMP(T) so HBM/L2 latency hides under the 128-FMA inner loop; the
    // __syncthreads drain (vmcnt 0) lands after the compute.
    #define SWEEP(K)                                                          \
    do {                                                                      \
        if ((K) > 0) {                                                        \
            _Pragma("unroll")                                                 \
            for (int bi = 0; bi < 4; ++bi)                                    \
                _Pragma("unroll")                                             \
                for (int k2 = 0; k2 < 4; ++k2)                                \
                    vs[bi][k2] = vlds[(bp * 4 + bi) * 16 + mq * 4 + k2];      \
        }                                                                     \
        _Pragma("unroll")                                                     \
        for (int bi = 0; bi < 4; ++bi) {                                      \
            den[bi] = 0.0f;                                                   \
            _Pragma("unroll")                                                 \
            for (int k2 = 0; k2 < 4; ++k2) st[bi][k2] = 0.0f;                 \
        }                                                                     \
        STAGE(0, 0);                                                          \
        __syncthreads();                                                      \
        _Pragma("unroll 1")                                                   \
        for (int t2 = 0; t2 < NTILE / 2; ++t2) {                              \
            const int Ta = 2 * t2, Tb = Ta + 1;                               \
            STAGE(1, Tb);                                                     \
            COMP(0, K, Ta);                                                   \
            __syncthreads();                                                  \
            if (Tb < NTILE - 1) STAGE(0, Tb + 1);                             \
            COMP(1, K, Tb);                                                   \
            __syncthreads();                                                  \
        }                                                                     \
        REDUCE(K);                                                            \
    } while (0)

    SWEEP(0);
    SWEEP(1);
    SWEEP(2);

    #undef SWEEP
    #undef REDUCE
    #undef COMP
    #undef STAGE
}

extern "C" void kernel_launch(void* const* d_in, const int* in_sizes, int n_in,
                              void* d_out, int out_size, void* d_ws, size_t ws_size,
                              hipStream_t stream) {
    const float* u = (const float*)d_in[0];   // [128, 1152, 8]
    const float* w = (const float*)d_in[1];   // [1152, 32, 8, 16]
    float* out     = (float*)d_out;           // [128, 32, 16]
    (void)in_sizes; (void)n_in; (void)out_size; (void)d_ws; (void)ws_size;

    dim3 grid(OUT_CAPS * (B_SZ / GB));   // 32 j x 16 b-groups = 512 blocks
    dim3 block(THREADS);                 // 512 threads = 8 waves
    hipLaunchKernelGGL(caps_route, grid, block, 0, stream, u, w, out);
}